// Round 13
// baseline (147.001 us; speedup 1.0000x reference)
//
#include <hip/hip_runtime.h>
#include <math.h>

// Problem constants
#define B_TOT 2048
#define S_LEN 256
#define DIN   3
#define H     128
#define DOUT  6
#define DT_C  0.1f

#define NROWS 8    // batch rows per block (8 valid cols, duplicated into cols 8..15)
#define HPAD  136  // bf16 row stride in sh_h (128 + 8 pad), rows 16B-aligned
#define PPAD  132  // f32 row stride in sh_p (head staging only)

// scale folded into W_hh/W_xh/b_hh so epilogue uses exp2 directly:
// tanh(p) = 1 - 2/(exp2(p * 2*log2e)+1)
#define PRESCALE 2.8853900817779268f   // 2*log2(e)

typedef __attribute__((ext_vector_type(8))) short short8;
typedef __attribute__((ext_vector_type(4))) float f32x4;

__device__ __forceinline__ unsigned short f2bf(float f) {
  unsigned int u = __float_as_uint(f);
  u += 0x7FFFu + ((u >> 16) & 1u);          // round-to-nearest-even
  return (unsigned short)(u >> 16);
}
// pack two f32 -> two bf16 (RNE) in one dword
__device__ __forceinline__ unsigned int pack2_bf16(float a, float b) {
  unsigned int ua = __float_as_uint(a), ub = __float_as_uint(b);
  ua = ua + 0x7FFFu + ((ua >> 16) & 1u);
  ub = ub + 0x7FFFu + ((ub >> 16) & 1u);
  return (ua >> 16) | (ub & 0xFFFF0000u);
}
// float2 helpers (nudge v_pk_fma_f32)
__device__ __forceinline__ float2 fma2(float2 a, float2 b, float2 c) {
  return make_float2(__builtin_fmaf(a.x, b.x, c.x), __builtin_fmaf(a.y, b.y, c.y));
}

// One block = 8 batch rows, 512 threads (8 waves, 2/SIMD). Wave w owns j-tile
// [w*16, w*16+16); A = W_hh rows (PRESCALEd, plain bf16 RNE, register-resident).
//   MFMA: D[m=j_loc][n] ; lane holds (n = lane&15, j_loc = quad*4 + r).
// COLUMN DUPLICATION: all 64 lanes read the B-fragment of row (l16&7) — lanes b
// and b+8 fetch identical LDS addresses (broadcast, conflict-free), so D cols
// 8..15 duplicate cols 0..7 and EVERY lane holds the full 4-reg preact for its
// own batch row. Dense epilogue = register select by rbse (no DPP, no exec mask):
// lane owns (b = l16&7, j = w*16 + quad*4 + (l16>>3)*2 + {0,1}) for all 256 steps.
// ONE barrier per step; ping-pong h buffers; step pair shares float2 x loads.
__launch_bounds__(512, 2)
__global__ void ltc_kernel(const float* __restrict__ x,
                           const float* __restrict__ W_xh,
                           const float* __restrict__ W_hh,
                           const float* __restrict__ b_hh,
                           const float* __restrict__ log_tau,
                           const float* __restrict__ fc_W,
                           const float* __restrict__ fc_b,
                           float* __restrict__ out) {
  __shared__ alignas(16) unsigned short sh_h[2][NROWS][HPAD];  // ping-pong h bf16
  __shared__ alignas(16) float sh_p[NROWS][PPAD];              // final h fp32 for head

  const int tid  = threadIdx.x;
  const int w    = tid >> 6;        // wave 0..7 -> j-tile [w*16, w*16+16)
  const int lane = tid & 63;
  const int quad = lane >> 4;       // 0..3
  const int l16  = lane & 15;       // column in B/D fragments
  const int rb0  = blockIdx.x * NROWS;

  // ---- zero both h buffers ----
  {
    uint4* p = (uint4*)&sh_h[0][0][0];
    const int n16 = (2 * NROWS * HPAD) / 8;  // shorts -> uint4 count
    for (int i = tid; i < n16; i += 512) p[i] = make_uint4(0, 0, 0, 0);
  }

  // ---- W_hh A-fragments (PRESCALE*W, RNE bf16), register-resident ----
  // A[m=l16][k = kc*32 + quad*8 + i],  j = w*16 + m
  short8 wa[4];
  {
    const int j = w * 16 + l16;
#pragma unroll
    for (int kc = 0; kc < 4; ++kc) {
      const float* src = W_hh + j * H + kc * 32 + quad * 8;
#pragma unroll
      for (int i = 0; i < 8; ++i)
        wa[kc][i] = (short)f2bf(src[i] * PRESCALE);
    }
  }

  // ---- dense epilogue mapping: lane owns (b = l16&7, j = w*16+quad*4+(l16>>3)*2+{0,1}) ----
  const int brow = l16 & 7;
  const int rbse = (l16 >> 3) * 2;            // reg-pair select: 0 (lanes b) / 2 (lanes b+8)
  float2 ewxv[3], ebhv, eccv, eav, encc2v;
  {
    float tmp[2][6];
#pragma unroll
    for (int r = 0; r < 2; ++r) {
      const int j = w * 16 + quad * 4 + rbse + r;
      tmp[r][0] = W_xh[j * 3 + 0] * PRESCALE;
      tmp[r][1] = W_xh[j * 3 + 1] * PRESCALE;
      tmp[r][2] = W_xh[j * 3 + 2] * PRESCALE;
      tmp[r][3] = b_hh[j] * PRESCALE;
      float lt  = log_tau[j];
      float tau = logf(1.f + expf(lt)) + 0.001f;   // softplus + eps, exact fp32, once
      tmp[r][4] = DT_C / tau;
      tmp[r][5] = 0.f;
    }
    ewxv[0] = make_float2(tmp[0][0], tmp[1][0]);
    ewxv[1] = make_float2(tmp[0][1], tmp[1][1]);
    ewxv[2] = make_float2(tmp[0][2], tmp[1][2]);
    ebhv    = make_float2(tmp[0][3], tmp[1][3]);
    eccv    = make_float2(tmp[0][4], tmp[1][4]);
    eav     = make_float2(1.f - tmp[0][4], 1.f - tmp[1][4]);
    encc2v  = make_float2(-2.f * tmp[0][4], -2.f * tmp[1][4]);
  }
  const float* xp = x + (size_t)(rb0 + brow) * (S_LEN * DIN);

  float2 hv = make_float2(0.f, 0.f);  // fp32 h for (brow, j..j+1), register-resident

  // static LDS offsets (shorts)
  const int rd_off = brow * HPAD + quad * 8;                    // B-frag read (+ kc*32), ALL lanes
  const int wr_off = brow * HPAD + w * 16 + quad * 4 + rbse;    // dense 4B h' store
  const unsigned short* __restrict__ buf0 = &sh_h[0][0][0];
  unsigned short* __restrict__ buf1 = &sh_h[1][0][0];

  // x prefetch: 6 floats per 2-step pair as 3x float2 (24B step-pair stride)
  float2 pfa = *(const float2*)(xp);
  float2 pfb = *(const float2*)(xp + 2);
  float2 pfc = *(const float2*)(xp + 4);

  __syncthreads();

  auto do_step = [&](const unsigned short* __restrict__ cur,
                     unsigned short* __restrict__ nxt,
                     float xc0, float xc1, float xc2) {
    // B-fragments of h^T: all 64 lanes, row brow (cols 8..15 duplicate 0..7 -> broadcast)
    short8 bf[4];
#pragma unroll
    for (int kc = 0; kc < 4; ++kc)
      bf[kc] = *(const short8*)(cur + rd_off + kc * 32);

    // x-projection terms for this lane's 2 elems (packed f32; hidden under ds_read latency)
    float2 t = fma2(make_float2(xc2, xc2), ewxv[2], ebhv);
    t = fma2(make_float2(xc1, xc1), ewxv[1], t);
    t = fma2(make_float2(xc0, xc0), ewxv[0], t);

    // single 4-deep MFMA chain (plain bf16 W)
    f32x4 ah = {0.f, 0.f, 0.f, 0.f};
#pragma unroll
    for (int kc = 0; kc < 4; ++kc)
      ah = __builtin_amdgcn_mfma_f32_16x16x32_bf16(wa[kc], bf[kc], ah, 0, 0, 0);

    // register select: every lane holds its row's full preact; pick pair by rbse
    float pre0 = (rbse == 0) ? ah[0] : ah[2];
    float pre1 = (rbse == 0) ? ah[1] : ah[3];

    // dense epilogue: 2 elems/lane, every lane (packed full-rate, scalar transcendentals)
    float e0  = __builtin_amdgcn_exp2f(pre0 + t.x);
    float e1  = __builtin_amdgcn_exp2f(pre1 + t.y);
    float rc0 = __builtin_amdgcn_rcpf(e0 + 1.f);
    float rc1 = __builtin_amdgcn_rcpf(e1 + 1.f);
    hv = fma2(encc2v, make_float2(rc0, rc1), fma2(hv, eav, eccv));

    *(unsigned int*)(nxt + wr_off) = pack2_bf16(hv.x, hv.y);  // dense 4B store
    __syncthreads();
  };

  for (int s = 0; s < S_LEN; s += 2) {
    float2 xa = pfa, xb = pfb, xc = pfc;
    if (s + 2 < S_LEN) {           // uniform branch; prefetch next pair
      xp += 6;
      pfa = *(const float2*)(xp);
      pfb = *(const float2*)(xp + 2);
      pfc = *(const float2*)(xp + 4);
    }
    do_step(buf0, buf1, xa.x, xa.y, xb.x);
    do_step(buf1, (unsigned short*)buf0, xb.y, xc.x, xc.y);
  }

  // ---- final head: params = softplus(h @ fc_W^T + fc_b), [8 x 6] per block ----
  // lanes b and b+8 hold identical (b,j) pairs -> let low half write (benign dup otherwise)
  {
    float2 v = hv;
    *(float2*)&sh_p[brow][w * 16 + quad * 4 + rbse] = v;   // 8B-aligned
  }
  __syncthreads();

  if (tid < NROWS * DOUT) {
    const int b = tid / DOUT;
    const int o = tid - b * DOUT;
    const float* fw = fc_W + o * H;
    float acc = fc_b[o];
#pragma unroll 4
    for (int k = 0; k < H; ++k) acc += sh_p[b][k] * fw[k];
    float sp = (acc > 15.f) ? acc : logf(1.f + expf(acc));
    out[(rb0 + b) * DOUT + o] = sp;
  }
}

extern "C" void kernel_launch(void* const* d_in, const int* in_sizes, int n_in,
                              void* d_out, int out_size, void* d_ws, size_t ws_size,
                              hipStream_t stream) {
  const float* x       = (const float*)d_in[0];
  const float* W_xh    = (const float*)d_in[1];
  const float* W_hh    = (const float*)d_in[2];
  const float* b_hh    = (const float*)d_in[3];
  const float* log_tau = (const float*)d_in[4];
  const float* fc_W    = (const float*)d_in[5];
  const float* fc_b    = (const float*)d_in[6];
  float* out           = (float*)d_out;

  ltc_kernel<<<dim3(B_TOT / NROWS), dim3(512), 0, stream>>>(
      x, W_xh, W_hh, b_hh, log_tau, fc_W, fc_b, out);
}